// Round 1
// baseline (411.454 us; speedup 1.0000x reference)
//
#include <hip/hip_runtime.h>

#define EMB_DIM 64
#define FM_K 10
#define AVG_RATING 4.0f

__global__ __launch_bounds__(256) void decoder_fm_kernel(
    const int*   __restrict__ user,
    const int*   __restrict__ item,
    const float* __restrict__ user_emb,
    const float* __restrict__ item_emb,
    const float* __restrict__ fc_w,
    const float* __restrict__ fc_b,
    const float* __restrict__ fm_V,
    const float* __restrict__ b_users,
    const float* __restrict__ b_items,
    float*       __restrict__ out,
    int B)
{
    // one 64-lane wave per sample
    const int wave = (int)((blockIdx.x * blockDim.x + threadIdx.x) >> 6);
    const int lane = threadIdx.x & 63;
    if (wave >= B) return;

    const int uidx = user[wave];
    const int iidx = item[wave];

    // coalesced 256B row gathers: lane l reads element l of each row
    const float x0 = user_emb[(size_t)uidx * EMB_DIM + lane];
    const float x1 = item_emb[(size_t)iidx * EMB_DIM + lane];

    // per-lane V rows (5KB table, L1-resident)
    float v0[FM_K], v1[FM_K];
#pragma unroll
    for (int k = 0; k < FM_K; ++k) {
        v0[k] = fm_V[lane * FM_K + k];
        v1[k] = fm_V[(lane + EMB_DIM) * FM_K + k];
    }

    // 12 reduction values: xv[0..9], linear, x^2*sumV2
    float red[FM_K + 2];
    float sv2_0 = 0.f, sv2_1 = 0.f;
#pragma unroll
    for (int k = 0; k < FM_K; ++k) {
        red[k] = x0 * v0[k] + x1 * v1[k];
        sv2_0 += v0[k] * v0[k];
        sv2_1 += v1[k] * v1[k];
    }
    red[FM_K]     = x0 * fc_w[lane] + x1 * fc_w[lane + EMB_DIM];
    red[FM_K + 1] = x0 * x0 * sv2_0 + x1 * x1 * sv2_1;

    // butterfly reduction across the 64-lane wave
#pragma unroll
    for (int off = 32; off > 0; off >>= 1) {
#pragma unroll
        for (int r = 0; r < FM_K + 2; ++r)
            red[r] += __shfl_xor(red[r], off, 64);
    }

    if (lane == 0) {
        float inter = 0.f;
#pragma unroll
        for (int k = 0; k < FM_K; ++k) inter += red[k] * red[k];
        inter = 0.5f * (inter - red[FM_K + 1]);
        out[wave] = inter + red[FM_K] + fc_b[0]
                  + b_users[uidx] + b_items[iidx] + AVG_RATING;
    }
}

extern "C" void kernel_launch(void* const* d_in, const int* in_sizes, int n_in,
                              void* d_out, int out_size, void* d_ws, size_t ws_size,
                              hipStream_t stream) {
    const int*   user     = (const int*)  d_in[0];
    const int*   item     = (const int*)  d_in[1];
    // d_in[2] = u_out, d_in[3] = i_out : multiplied by 0 in the reference, never read
    const float* user_emb = (const float*)d_in[4];
    const float* item_emb = (const float*)d_in[5];
    const float* fc_w     = (const float*)d_in[6];
    const float* fc_b     = (const float*)d_in[7];
    const float* fm_V     = (const float*)d_in[8];
    const float* b_users  = (const float*)d_in[9];
    const float* b_items  = (const float*)d_in[10];
    float* out = (float*)d_out;

    const int B = in_sizes[0];
    const int threads = 256;                       // 4 waves/block, 1 sample/wave
    const int blocks  = (B * 64 + threads - 1) / threads;
    decoder_fm_kernel<<<blocks, threads, 0, stream>>>(
        user, item, user_emb, item_emb, fc_w, fc_b, fm_V, b_users, b_items, out, B);
}